// Round 6
// baseline (231.499 us; speedup 1.0000x reference)
//
#include <hip/hip_runtime.h>

#define HH 512
#define WW 512
#define HW (HH*WW)
#define EPV 1e-20f

// Box window for center (y,x): rows y-3..y+4, cols x-3..x+4, zero-padded
// (verified absmax 0.0 R1-R4, 0.0078 R5 streaming form). Streaming:
//   h(row r, lane l) = sum_{d=1..8} v(r, l+d)   [horizontal, via bpermute]
//   S(y) = sum_{c=y-3..y+4} h(c)                [vertical, register ring]

__device__ __forceinline__ float bpf(int addr, float v) {
    return __int_as_float(__builtin_amdgcn_ds_bpermute(addr, __float_as_int(v)));
}

// h(l) = sum_{d=1..8} v(l+d); valid for lanes l <= 55 (wave64).
__device__ __forceinline__ float win8(float v, int a1, int a2, int a4) {
    float t = v + bpf(a1, v);
    t = t + bpf(a2, t);
    t = t + bpf(a4, t);
    return bpf(a1, t);
}

// ---------------- prep: raw -> centered (ac/bc) + variance box (sii/sjj) ----
// 4 waves/block, one wave per (image z, 48-col strip, 32-row seg).
// Stream t=0..46: stage1 mean cascade, stage2 sii cascade (ring buffers).
__global__ __launch_bounds__(256) void prep_stream(
    const float* __restrict__ outs, const float* __restrict__ labs,
    float* __restrict__ ac, float* __restrict__ bc,
    float* __restrict__ sii, float* __restrict__ sjj)
{
    const int tid = threadIdx.x;
    const int l = tid & 63, w = tid >> 6;
    const int x0 = 48 * blockIdx.x;               // strip start (output cols)
    const int y0 = 32 * (blockIdx.y * 4 + w);     // seg start (output rows)
    const int z  = blockIdx.z;

    const float* src; float* cdst; float* sdst;
    if (z < 24) { src = outs + z * HW; cdst = ac + z * HW; sdst = sii + z * HW; }
    else { int u = z - 24; src = labs + u * HW; cdst = bc + u * HW; sdst = sjj + u * HW; }

    const int   gin  = x0 - 4 + l;
    const int   ginc = min(max(gin, 0), WW - 1);
    const float minA = (gin >= 0 && gin < WW) ? 1.f : 0.f;
    const int   a1 = ((l + 1) & 63) << 2, a2 = ((l + 2) & 63) << 2, a4 = ((l + 4) & 63) << 2;

    const bool st_c = (l >= 4 && l < 52 && gin < WW);   // ac store lanes
    const int  gout = x0 + l;
    const bool st_s = (l < 48 && gout < WW);            // sii store lanes

    float araw[8], ha8[8], hii8[8];
    #pragma unroll
    for (int k = 0; k < 8; ++k) { araw[k] = 0.f; ha8[k] = 0.f; hii8[k] = 0.f; }
    float VA = 0.f, VSII = 0.f;

    auto step = [&](int t, int k) {
        const int r = y0 - 7 + t;                       // stage-1 input row
        float av = 0.f;
        if (r >= 0 && r < HH) av = src[r * WW + ginc] * minA;
        float han = win8(av, a1, a2, a4);
        VA += han - ha8[k]; ha8[k] = han;               // box rows c-3..c+4
        float aold = araw[(k + 4) & 7];                 // raw row c = r-4
        araw[k] = av;
        if (t >= 8) {
            const int c = r - 4;
            float acv = 0.f;
            if (c >= 0 && c < HH) acv = (aold - VA * (1.f / 64.f)) * minA;
            if (c >= y0 && c < y0 + 32 && st_c)
                cdst[c * WW + gin] = acv;
            float hin = win8(acv * acv, a1, a2, a4);
            VSII += hin - hii8[k]; hii8[k] = hin;       // box rows y-3..y+4
            if (t >= 15) {
                const int y = c - 4;                    // y in [y0, y0+31]
                if (st_s) sdst[y * WW + gout] = fmaxf(VSII, EPV);
            }
        }
    };

    for (int g = 0; g < 5; ++g) {
        #pragma unroll
        for (int k = 0; k < 8; ++k) step(g * 8 + k, k);
    }
    #pragma unroll
    for (int k = 0; k < 7; ++k) step(40 + k, k);        // t = 40..46; 40&7==0
}

// ---------------- main: sij streaming, all 4 j per wave --------------------
// 4 waves/block, one wave per (z=b*6+i, 56-col strip, 16-row seg).
// Stream t=0..22. Zero barriers, zero LDS arrays.
__global__ __launch_bounds__(256) void ncc_stream(
    const float* __restrict__ ac, const float* __restrict__ bc,
    const float* __restrict__ sii, const float* __restrict__ sjj,
    float* __restrict__ out)
{
    const int tid = threadIdx.x;
    const int l = tid & 63, w = tid >> 6;
    const int x0 = 56 * blockIdx.x;
    const int y0 = 16 * (blockIdx.y * 4 + w);
    const int z  = blockIdx.z;               // b*6 + i
    const int b  = z / 6;

    const float* acp = ac  + z * HW;
    const float* sip = sii + z * HW;
    const float* bcp[4]; const float* sjp[4];
    #pragma unroll
    for (int j = 0; j < 4; ++j) {
        bcp[j] = bc  + (b * 4 + j) * HW;
        sjp[j] = sjj + (b * 4 + j) * HW;
    }

    const int   gin  = x0 - 4 + l;
    const int   ginc = min(max(gin, 0), WW - 1);
    const float minA = (gin >= 0 && gin < WW) ? 1.f : 0.f;
    const int   gout = x0 + l;
    const int   goutc = min(gout, WW - 1);
    const float outm = (l < 56 && gout < WW) ? 1.f : 0.f;
    const int   a1 = ((l + 1) & 63) << 2, a2 = ((l + 2) & 63) << 2, a4 = ((l + 4) & 63) << 2;

    float ring[4][8], VS[4];
    #pragma unroll
    for (int j = 0; j < 4; ++j) {
        VS[j] = 0.f;
        #pragma unroll
        for (int k = 0; k < 8; ++k) ring[j][k] = 0.f;
    }
    float xs = 0.f;

    auto step = [&](int t, int k) {
        const int c = y0 - 3 + t;                        // product row
        float av = 0.f, bv[4] = {0.f, 0.f, 0.f, 0.f};
        if (c >= 0 && c < HH) {
            const int ro = c * WW + ginc;
            av = acp[ro] * minA;
            #pragma unroll
            for (int j = 0; j < 4; ++j) bv[j] = bcp[j][ro] * minA;
        }
        #pragma unroll
        for (int j = 0; j < 4; ++j) {
            float h = win8(av * bv[j], a1, a2, a4);
            VS[j] += h - ring[j][k]; ring[j][k] = h;     // box rows c-7..c
        }
        if (t >= 7) {
            const int y  = y0 + t - 7;                   // = c-4, in [y0, y0+15]
            const int yo = y * WW + goutc;
            float si = sip[yo];
            float mm = -1.f;
            #pragma unroll
            for (int j = 0; j < 4; ++j) {
                float sj = sjp[j][yo];
                float cc = VS[j] * __frsqrt_rn(fmaxf(si * sj, 1e-37f));
                mm = fmaxf(mm, cc);
            }
            xs += outm * (1.f - fminf(mm, 1.f));
        }
    };

    for (int g = 0; g < 2; ++g) {
        #pragma unroll
        for (int k = 0; k < 8; ++k) step(g * 8 + k, k);
    }
    #pragma unroll
    for (int k = 0; k < 7; ++k) step(16 + k, k);         // t = 16..22; 16&7==0

    #pragma unroll
    for (int off = 32; off > 0; off >>= 1) xs += __shfl_down(xs, off);
    if (l == 0) atomicAdd(&out[1 + z], xs * (1.f / (float)HW));
}

__global__ void finalize_kernel(float* __restrict__ out)
{
    if (threadIdx.x == 0) {
        float s = 0.f;
        #pragma unroll
        for (int z = 0; z < 24; ++z) s += out[1 + z];
        out[0] = s * (1.0f / 24.0f);
    }
}

extern "C" void kernel_launch(void* const* d_in, const int* in_sizes, int n_in,
                              void* d_out, int out_size, void* d_ws, size_t ws_size,
                              hipStream_t stream) {
    const float* outs = (const float*)d_in[0];   // (4,6,512,512)
    const float* labs = (const float*)d_in[1];   // (4,4,512,512)
    float* out = (float*)d_out;                  // 25 floats
    float* ws  = (float*)d_ws;

    float* acw = ws;                 // 24*HW
    float* bcw = acw + 24 * HW;      // 16*HW
    float* siw = bcw + 16 * HW;      // 24*HW
    float* sjw = siw + 24 * HW;      // 16*HW

    hipMemsetAsync(d_out, 0, out_size * sizeof(float), stream);

    // prep: 11 strips x (4 groups x 4 waves -> 16 segs of 32 rows) x 40 images
    prep_stream<<<dim3(11, 4, 40), 256, 0, stream>>>(outs, labs, acw, bcw, siw, sjw);
    // main: 10 strips x (8 groups x 4 waves -> 32 segs of 16 rows) x 24 (b,i)
    ncc_stream<<<dim3(10, 8, 24), 256, 0, stream>>>(acw, bcw, siw, sjw, out);
    finalize_kernel<<<1, 64, 0, stream>>>(out);
}